// Round 1
// baseline (156.771 us; speedup 1.0000x reference)
//
#include <hip/hip_runtime.h>
#include <hip/hip_bf16.h>

typedef __attribute__((ext_vector_type(8))) short short8;  // 8 bf16 (4 VGPRs)
typedef __attribute__((ext_vector_type(4))) float f32x4;

#define INF_BITS 0x7F800000u

// ---------------------------------------------------------------------------
// prep: fp32 -> bf16 conversion, exact fp32 row norms, init min arrays to +inf
// one wave per row (D=64 -> one element per lane)
// ---------------------------------------------------------------------------
__global__ __launch_bounds__(256) void ahd_prep(
    const float* __restrict__ s1, const float* __restrict__ s2,
    __hip_bfloat16* __restrict__ abf, __hip_bfloat16* __restrict__ bbf,
    float* __restrict__ x2, float* __restrict__ y2,
    unsigned int* __restrict__ rmin, unsigned int* __restrict__ cmin,
    int N, int M)
{
    const int tid  = threadIdx.x;
    const int lane = tid & 63;
    const int w    = tid >> 6;

    // init global min arrays (first (N+M)/256 blocks cover all entries)
    const int t = blockIdx.x * 256 + tid;
    if (t < N)          rmin[t]     = INF_BITS;
    else if (t < N + M) cmin[t - N] = INF_BITS;

    const int gw = blockIdx.x * 4 + w;   // global wave index == row index
    if (gw < N) {
        float v = s1[(size_t)gw * 64 + lane];
        abf[(size_t)gw * 64 + lane] = __float2bfloat16(v);
        float ss = v * v;
        #pragma unroll
        for (int s = 1; s < 64; s <<= 1) ss += __shfl_xor(ss, s);
        if (lane == 0) x2[gw] = ss;
    } else if (gw < N + M) {
        const int r = gw - N;
        float v = s2[(size_t)r * 64 + lane];
        bbf[(size_t)r * 64 + lane] = __float2bfloat16(v);
        float ss = v * v;
        #pragma unroll
        for (int s = 1; s < 64; s <<= 1) ss += __shfl_xor(ss, s);
        if (lane == 0) y2[r] = ss;
    }
}

// ---------------------------------------------------------------------------
// fused distance-GEMM + row/col min. 128x128 tile per block, K=64 (one pass).
// 256 threads = 4 waves in 2x2; each wave owns a 64x64 sub-tile (4x4 frags of
// mfma_f32_16x16x32_bf16). Min over SQUARED distances (sqrt deferred).
// ---------------------------------------------------------------------------
__global__ __launch_bounds__(256) void ahd_gemm(
    const __hip_bfloat16* __restrict__ abf, const __hip_bfloat16* __restrict__ bbf,
    const float* __restrict__ x2, const float* __restrict__ y2,
    unsigned int* __restrict__ rmin, unsigned int* __restrict__ cmin)
{
    __shared__ __attribute__((aligned(128))) char lds[32768]; // A 16K | B 16K
    __shared__ unsigned int lmin[256];  // [0:128) row mins, [128:256) col mins

    const int tid  = threadIdx.x;
    const int lane = tid & 63;
    const int w    = tid >> 6;
    const int wr = w >> 1, wc = w & 1;       // wave 2x2 position
    const int lr = lane & 15, lh = lane >> 4;

    const int brow = blockIdx.x * 128;
    const int bcol = blockIdx.y * 128;

    // tiles are contiguous 16 KB blocks in global (row-major [128][64] bf16)
    const char* aTile = (const char*)abf + (size_t)brow * 128;
    const char* bTile = (const char*)bbf + (size_t)bcol * 128;
    char* ldsA = lds;
    char* ldsB = lds + 16384;

    // stage: linear LDS dest + inverse-swizzled global source (involution)
    #pragma unroll
    for (int it = 0; it < 4; ++it) {
        const int dst = w * 1024 + it * 4096;        // wave-uniform LDS base
        const int o   = dst + lane * 16;             // linear dest byte offset
        const int so  = o ^ ((o >> 3) & 0x70);       // swizzled source offset
        __builtin_amdgcn_global_load_lds(
            (const __attribute__((address_space(1))) void*)(aTile + so),
            (__attribute__((address_space(3))) void*)(ldsA + dst), 16, 0, 0);
        __builtin_amdgcn_global_load_lds(
            (const __attribute__((address_space(1))) void*)(bTile + so),
            (__attribute__((address_space(3))) void*)(ldsB + dst), 16, 0, 0);
    }

    f32x4 acc[4][4];
    #pragma unroll
    for (int m = 0; m < 4; ++m)
        #pragma unroll
        for (int n = 0; n < 4; ++n)
            acc[m][n] = (f32x4){0.f, 0.f, 0.f, 0.f};

    __syncthreads();

    // K loop: 2 steps of K=32. A frag: lane holds A[row=lr][k=lh*8..+8];
    // B frag: lane holds B[k=lh*8..+8][col=lr] = set2[col][k] (B^T layout).
    #pragma unroll
    for (int ks = 0; ks < 2; ++ks) {
        short8 af[4], bf[4];
        #pragma unroll
        for (int m = 0; m < 4; ++m) {
            int o = (wr * 64 + m * 16 + lr) * 128 + ks * 64 + lh * 16;
            o ^= (o >> 3) & 0x70;
            af[m] = *(const short8*)(ldsA + o);
        }
        #pragma unroll
        for (int n = 0; n < 4; ++n) {
            int o = (wc * 64 + n * 16 + lr) * 128 + ks * 64 + lh * 16;
            o ^= (o >> 3) & 0x70;
            bf[n] = *(const short8*)(ldsB + o);
        }
        #pragma unroll
        for (int m = 0; m < 4; ++m)
            #pragma unroll
            for (int n = 0; n < 4; ++n)
                acc[m][n] = __builtin_amdgcn_mfma_f32_16x16x32_bf16(
                                af[m], bf[n], acc[m][n], 0, 0, 0);
    }

    // epilogue: d2 = x2[i] + y2[j] - 2*dot ; min over d2 (sqrt deferred).
    // C/D layout (m89): col = lane&15, row = (lane>>4)*4 + reg.
    float xv[4][4], yv[4];
    #pragma unroll
    for (int m = 0; m < 4; ++m)
        #pragma unroll
        for (int j = 0; j < 4; ++j)
            xv[m][j] = x2[brow + wr * 64 + m * 16 + lh * 4 + j];
    #pragma unroll
    for (int n = 0; n < 4; ++n)
        yv[n] = y2[bcol + wc * 64 + n * 16 + lr];

    float colm[4] = {1e30f, 1e30f, 1e30f, 1e30f};
    float rowm[4][4];
    #pragma unroll
    for (int m = 0; m < 4; ++m) {
        #pragma unroll
        for (int j = 0; j < 4; ++j) {
            float rm = 1e30f;
            const float xvv = xv[m][j];
            #pragma unroll
            for (int n = 0; n < 4; ++n) {
                const float d2 = fmaf(-2.f, acc[m][n][j], xvv + yv[n]);
                rm = fminf(rm, d2);
                colm[n] = fminf(colm[n], d2);
            }
            rowm[m][j] = rm;
        }
    }

    // row-min: reduce across the 16 lanes sharing a row (xor 1,2,4,8)
    #pragma unroll
    for (int m = 0; m < 4; ++m)
        #pragma unroll
        for (int j = 0; j < 4; ++j) {
            float v = rowm[m][j];
            v = fminf(v, __shfl_xor(v, 1));
            v = fminf(v, __shfl_xor(v, 2));
            v = fminf(v, __shfl_xor(v, 4));
            v = fminf(v, __shfl_xor(v, 8));
            rowm[m][j] = fmaxf(v, 0.f);   // clamp once, post-reduce
        }
    // col-min: reduce across the 4 lane-groups sharing a col (xor 16,32)
    #pragma unroll
    for (int n = 0; n < 4; ++n) {
        float v = colm[n];
        v = fminf(v, __shfl_xor(v, 16));
        v = fminf(v, __shfl_xor(v, 32));
        colm[n] = fmaxf(v, 0.f);
    }

    // cross-wave combine in LDS (u32 min == f32 min for non-negative floats)
    lmin[tid] = INF_BITS;
    __syncthreads();
    if (lr == 0) {
        #pragma unroll
        for (int m = 0; m < 4; ++m)
            #pragma unroll
            for (int j = 0; j < 4; ++j)
                atomicMin(&lmin[wr * 64 + m * 16 + lh * 4 + j],
                          __float_as_uint(rowm[m][j]));
    }
    if (lh == 0) {
        #pragma unroll
        for (int n = 0; n < 4; ++n)
            atomicMin(&lmin[128 + wc * 64 + n * 16 + lr],
                      __float_as_uint(colm[n]));
    }
    __syncthreads();

    if (tid < 128) atomicMin(&rmin[brow + tid],         lmin[tid]);
    else           atomicMin(&cmin[bcol + (tid - 128)], lmin[tid]);
}

// ---------------------------------------------------------------------------
// finalize: out = mean(sqrt(rmin)) + mean(sqrt(cmin)); single block.
// ---------------------------------------------------------------------------
__global__ __launch_bounds__(256) void ahd_finalize(
    const unsigned int* __restrict__ rmin, const unsigned int* __restrict__ cmin,
    float* __restrict__ out, int N, int M)
{
    const int tid = threadIdx.x;
    float sa = 0.f, sb = 0.f;
    for (int i = tid; i < N; i += 256) sa += sqrtf(__uint_as_float(rmin[i]));
    for (int i = tid; i < M; i += 256) sb += sqrtf(__uint_as_float(cmin[i]));
    float v = sa / (float)N + sb / (float)M;
    #pragma unroll
    for (int s = 1; s < 64; s <<= 1) v += __shfl_xor(v, s);
    __shared__ float red[4];
    if ((tid & 63) == 0) red[tid >> 6] = v;
    __syncthreads();
    if (tid == 0) out[0] = red[0] + red[1] + red[2] + red[3];
}

extern "C" void kernel_launch(void* const* d_in, const int* in_sizes, int n_in,
                              void* d_out, int out_size, void* d_ws, size_t ws_size,
                              hipStream_t stream) {
    const float* s1 = (const float*)d_in[0];
    const float* s2 = (const float*)d_in[1];
    const int N = in_sizes[0] / 64;
    const int M = in_sizes[1] / 64;

    // workspace layout (needs ~4.25 MB):
    //   abf: N*64 bf16 | bbf: M*64 bf16 | x2: N f32 | y2: M f32
    //   rmin: N u32 | cmin: M u32
    char* ws = (char*)d_ws;
    __hip_bfloat16* abf = (__hip_bfloat16*)ws;
    __hip_bfloat16* bbf = (__hip_bfloat16*)(ws + (size_t)N * 128);
    float* x2 = (float*)(ws + (size_t)(N + M) * 128);
    float* y2 = x2 + N;
    unsigned int* rmin = (unsigned int*)(y2 + M);
    unsigned int* cmin = rmin + N;

    const int rows = N + M;
    ahd_prep<<<(rows + 3) / 4, 256, 0, stream>>>(s1, s2, abf, bbf, x2, y2,
                                                 rmin, cmin, N, M);
    dim3 grid(N / 128, M / 128);
    ahd_gemm<<<grid, 256, 0, stream>>>(abf, bbf, x2, y2, rmin, cmin);
    ahd_finalize<<<1, 256, 0, stream>>>(rmin, cmin, (float*)d_out, N, M);
}